// Round 7
// baseline (98.520 us; speedup 1.0000x reference)
//
#include <hip/hip_runtime.h>

typedef float f32x4 __attribute__((ext_vector_type(4)));
typedef float f32x2 __attribute__((ext_vector_type(2)));

#define T_LEN   262144
#define NTAG    128
#define LCH     8
#define BURN    8
#define NSTEP   16
#define NCHUNK  (T_LEN / LCH)        // 32768
#define NFWDB   512                  // 64 chunks / block
#define ROWS_PB 520                  // 512 own + 8 burn-head rows
#define C5      3.465735902799726f   // 5 ln2  (E scale 2^-5)
#define C4      2.772588722239781f   // 4 ln2  (A scale 2^-4; total 2^-9/step)
#define K63LN2  43.66827237527655f   // 63 ln2
#define K72LN2  49.90659700060892f   // 72 ln2

// ---------------------------------------------------------------------------
// Setup: A = exp(trans - 4ln2) packed to fp8 A-fragments (R6 layout).
// Byte j of tile (rt,kt): k = 32kt+4grp+(j&3)+16*(j>>2), row = 16rt+col.
// ---------------------------------------------------------------------------
__global__ void crf_setup(const float* __restrict__ trans, uint4* __restrict__ q4)
{
  const int l = threadIdx.x;           // 64 threads
  const int col = l & 15, grp = l >> 4;
  for (int rt = 0; rt < 8; ++rt) {
    const int outtag = 16 * rt + col;
    for (int kp = 0; kp < 2; ++kp) {
      unsigned r[4];
      for (int h = 0; h < 2; ++h) {
        const int kt = kp * 2 + h;
        float q[8];
        for (int j = 0; j < 8; ++j) {
          const int k = 32 * kt + 4 * grp + (j & 3) + 16 * (j >> 2);
          q[j] = __expf(trans[k * NTAG + outtag] - C4);
        }
        unsigned lo = (unsigned)__builtin_amdgcn_cvt_pk_fp8_f32(q[0], q[1], 0, false);
        lo = (unsigned)__builtin_amdgcn_cvt_pk_fp8_f32(q[2], q[3], (int)lo, true);
        unsigned hi = (unsigned)__builtin_amdgcn_cvt_pk_fp8_f32(q[4], q[5], 0, false);
        hi = (unsigned)__builtin_amdgcn_cvt_pk_fp8_f32(q[6], q[7], (int)hi, true);
        r[h * 2] = lo; r[h * 2 + 1] = hi;
      }
      q4[(rt * 2 + kp) * 64 + l] = make_uint4(r[0], r[1], r[2], r[3]);
    }
  }
}

// ---------------------------------------------------------------------------
// Main: block = 4 waves = 64 chunks over rows [512b-8, 512b+512).
// Stage: linear 266 KB read -> E=fp8(exp(emit-5ln2)) in LDS (XOR-swizzled).
// Loop: 16 steps entirely from LDS; c = A x b (fp8 MFMA), w = c*E,
// rescale every 4th step (R6 telescoped accounting, unchanged constants).
// Score gathers folded into each block's own window. Ticket -> out.
// ---------------------------------------------------------------------------
__global__ __launch_bounds__(256, 2) void crf_main(
    const float* __restrict__ emit, const int* __restrict__ y,
    const float* __restrict__ trans, const float* __restrict__ strans,
    const float* __restrict__ etrans, const uint4* __restrict__ q4,
    double* __restrict__ ws, float* __restrict__ out)
{
  __shared__ unsigned int elds[ROWS_PB * 32];   // 66560 B

  const int tid = threadIdx.x;
  const int blk = blockIdx.x;

  // ---- stage E into LDS (fully coalesced linear global read) ----
  {
    const long rowbase = (long)blk * 512 - 8;
    const float4* em4 = (const float4*)emit;
#pragma unroll 4
    for (int i = 0; i < 65; ++i) {
      const int f  = tid + 256 * i;        // float4 index in window
      const int lr = f >> 5;               // local row
      const int q  = f & 31;               // tag group (tags 4q..4q+3)
      long grow = rowbase + lr; if (grow < 0) grow = 0;
      const float4 v = em4[grow * 32 + q];
      const float e0 = __expf(v.x - C5), e1 = __expf(v.y - C5);
      const float e2 = __expf(v.z - C5), e3 = __expf(v.w - C5);
      unsigned d = (unsigned)__builtin_amdgcn_cvt_pk_fp8_f32(e0, e1, 0, false);
      d = (unsigned)__builtin_amdgcn_cvt_pk_fp8_f32(e2, e3, (int)d, true);
      const int g = q & 3, rt = q >> 2;
      const int slot = (2 * g + (rt >> 2)) ^ ((lr >> 3) & 7);  // bank swizzle
      elds[lr * 32 + slot * 4 + (rt & 3)] = d;
    }
  }
  __syncthreads();

  // ---- forward: wave w owns chunks [blk*64+16w .. +16) ----
  const int w   = tid >> 6;
  const int l   = tid & 63;
  const int col = l & 15;
  const int g   = l >> 4;
  const int gw  = blk * 4 + w;
  const int gc  = gw * 16 + col;

  // A fragments: 16 coalesced dwordx4 loads
  long a[8][4];
#pragma unroll
  for (int rt = 0; rt < 8; ++rt)
#pragma unroll
    for (int kp = 0; kp < 2; ++kp) {
      uint4 v = q4[(rt * 2 + kp) * 64 + l];
      a[rt][2 * kp]     = (long)(((unsigned long long)v.y << 32) | v.x);
      a[rt][2 * kp + 1] = (long)(((unsigned long long)v.w << 32) | v.z);
    }

  // init state: chunk 0 exact; others p = 1
  float m0 = 0.f;
  long bb[4];
  {
    float u[8][4];
    if (gw == 0) {
      float vm = -1e30f;
#pragma unroll
      for (int rt = 0; rt < 8; ++rt)
#pragma unroll
        for (int r = 0; r < 4; ++r) {
          const int tag = 16 * rt + 4 * g + r;
          u[rt][r] = (col == 0) ? (strans[tag] + emit[tag]) : 0.f;
          vm = fmaxf(vm, u[rt][r]);
        }
      vm = fmaxf(vm, __shfl_xor(vm, 16, 64));
      vm = fmaxf(vm, __shfl_xor(vm, 32, 64));
      m0 = vm;
#pragma unroll
      for (int rt = 0; rt < 8; ++rt)
#pragma unroll
        for (int r = 0; r < 4; ++r)
          u[rt][r] = (col == 0) ? __expf(u[rt][r] - vm) : 1.0f;
    } else {
#pragma unroll
      for (int rt = 0; rt < 8; ++rt)
#pragma unroll
        for (int r = 0; r < 4; ++r) u[rt][r] = 1.0f;
    }
#pragma unroll
    for (int kt = 0; kt < 4; ++kt) {
      unsigned lo = (unsigned)__builtin_amdgcn_cvt_pk_fp8_f32(u[2*kt][0], u[2*kt][1], 0, false);
      lo = (unsigned)__builtin_amdgcn_cvt_pk_fp8_f32(u[2*kt][2], u[2*kt][3], (int)lo, true);
      unsigned hi = (unsigned)__builtin_amdgcn_cvt_pk_fp8_f32(u[2*kt+1][0], u[2*kt+1][1], 0, false);
      hi = (unsigned)__builtin_amdgcn_cvt_pk_fp8_f32(u[2*kt+1][2], u[2*kt+1][3], (int)hi, true);
      bb[kt] = (long)(((unsigned long long)hi << 32) | lo);
    }
  }

  // per-lane LDS row base: lr = lrb + s; chunk 0 reads rows 1..16 (lr 9..24)
  int lrb = (16 * w + col) * 8;
  if (gc == 0) lrb = 9;

  float acc = 0.f;

#pragma unroll
  for (int s = 0; s < NSTEP; ++s) {
    const int lr = lrb + s;
    const int sw = (lr >> 3) & 7;
    // E for this step: 2x ds_read_b128 (swizzled; structural bank minimum)
    const uint4 E0 = *(const uint4*)&elds[lr * 32 + (((2 * g + 0) ^ sw) << 2)];
    const uint4 E1 = *(const uint4*)&elds[lr * 32 + (((2 * g + 1) ^ sw) << 2)];

    // c = A x b
    f32x4 c[8];
#pragma unroll
    for (int rt = 0; rt < 8; ++rt) c[rt] = (f32x4){0.f, 0.f, 0.f, 0.f};
#pragma unroll
    for (int kt = 0; kt < 4; ++kt)
#pragma unroll
      for (int rt = 0; rt < 8; ++rt)
        c[rt] = __builtin_amdgcn_mfma_f32_16x16x32_fp8_fp8(a[rt][kt], bb[kt], c[rt], 0, 0, 0);

    // w = c * E  (fp8 -> f32 via pk cvt)
    float wv[8][4];
#pragma unroll
    for (int rt = 0; rt < 8; ++rt) {
      const unsigned dw = (rt < 4) ? ((const unsigned*)&E0)[rt & 3]
                                   : ((const unsigned*)&E1)[rt & 3];
      const f32x2 lo = __builtin_amdgcn_cvt_pk_f32_fp8((int)dw, false);
      const f32x2 hi = __builtin_amdgcn_cvt_pk_f32_fp8((int)dw, true);
      wv[rt][0] = c[rt][0] * lo[0];
      wv[rt][1] = c[rt][1] * lo[1];
      wv[rt][2] = c[rt][2] * hi[0];
      wv[rt][3] = c[rt][3] * hi[1];
    }

    // rescale every 4th step (exact, accounted)
    if ((s & 3) == 3) {
      float vm = wv[0][0];
#pragma unroll
      for (int rt = 0; rt < 8; ++rt)
#pragma unroll
        for (int r = 0; r < 4; ++r) vm = fmaxf(vm, wv[rt][r]);
      vm = fmaxf(vm, __shfl_xor(vm, 16, 64));
      vm = fmaxf(vm, __shfl_xor(vm, 32, 64));
      const float lv = __logf(vm);
      if (s == 3)  acc += (gc == 0) ? lv : 0.f;
      if (s == 11) acc += (gc != 0) ? lv : 0.f;
      if (s == 15) acc += (gc != 0) ? lv : 0.f;
      const float rinv = __builtin_amdgcn_rcpf(vm);
#pragma unroll
      for (int rt = 0; rt < 8; ++rt)
#pragma unroll
        for (int r = 0; r < 4; ++r) wv[rt][r] *= rinv;

      // final-state LSE (very last chunk, after last rescale)
      if (s == NSTEP - 1 && gw == (NCHUNK / 16) - 1) {
        float lse = 0.f;
#pragma unroll
        for (int rt = 0; rt < 8; ++rt)
#pragma unroll
          for (int r = 0; r < 4; ++r)
            lse += wv[rt][r] * __expf(etrans[16 * rt + 4 * g + r]);
        lse += __shfl_xor(lse, 16, 64);
        lse += __shfl_xor(lse, 32, 64);
        if (l == 15) atomicAdd(&ws[2], (double)lse);
      }
    }
    if (s == 6 && gw == 0) {   // chunk0 boundary norm (accounted, no rescale)
      float vm = wv[0][0];
#pragma unroll
      for (int rt = 0; rt < 8; ++rt)
#pragma unroll
        for (int r = 0; r < 4; ++r) vm = fmaxf(vm, wv[rt][r]);
      vm = fmaxf(vm, __shfl_xor(vm, 16, 64));
      vm = fmaxf(vm, __shfl_xor(vm, 32, 64));
      acc += (gc == 0) ? __logf(vm) : 0.f;
    }

    // pack b = fp8(w)
#pragma unroll
    for (int kt = 0; kt < 4; ++kt) {
      unsigned lo = (unsigned)__builtin_amdgcn_cvt_pk_fp8_f32(wv[2*kt][0], wv[2*kt][1], 0, false);
      lo = (unsigned)__builtin_amdgcn_cvt_pk_fp8_f32(wv[2*kt][2], wv[2*kt][3], (int)lo, true);
      unsigned hi = (unsigned)__builtin_amdgcn_cvt_pk_fp8_f32(wv[2*kt+1][0], wv[2*kt+1][1], 0, false);
      hi = (unsigned)__builtin_amdgcn_cvt_pk_fp8_f32(wv[2*kt+1][2], wv[2*kt+1][3], (int)hi, true);
      bb[kt] = (long)(((unsigned long long)hi << 32) | lo);
    }
  }

  // per-wave dc reduction (acc replicated across the 4 g-lanes per chunk)
  {
    const float accf = acc + ((gc == 0) ? (m0 + K63LN2) : K72LN2);
    float av = (g == 0) ? accf : 0.f;
#pragma unroll
    for (int off = 1; off < 64; off <<= 1) av += __shfl_xor(av, off, 64);
    if (l == 0) atomicAdd(&ws[0], (double)av);
  }

  // ---- score: this block's own 512 rows (L2-hot from staging) ----
  {
    float sv = 0.f;
#pragma unroll
    for (int ii = 0; ii < 2; ++ii) {
      const int t = blk * 512 + tid + 256 * ii;
      if (t < T_LEN - 1) {
        const int yt = y[t], yn = y[t + 1];
        sv += trans[yt * NTAG + yn] + emit[(size_t)t * NTAG + yt];
      }
    }
    if (blk == 0 && tid == 0) sv += strans[y[0]];
    if (blk == NFWDB - 1 && tid == 0) {
      const int yl = y[T_LEN - 1];
      sv += etrans[yl] + emit[(size_t)(T_LEN - 1) * NTAG + yl];
    }
#pragma unroll
    for (int off = 1; off < 64; off <<= 1) sv += __shfl_xor(sv, off, 64);
    if (l == 0) atomicAdd(&ws[1], (double)sv);
  }

  // ---- completion: last block writes the output ----
  __syncthreads();
  if (tid == 0) {
    __threadfence();
    const unsigned t = atomicAdd((unsigned*)&ws[3], 1u);
    if (t == NFWDB - 1) {
      const double d0 = atomicAdd(&ws[0], 0.0);
      const double d1 = atomicAdd(&ws[1], 0.0);
      const double d2 = atomicAdd(&ws[2], 0.0);
      out[0] = (float)(d0 + log(d2) - d1);
    }
  }
}

// ---------------------------------------------------------------------------
extern "C" void kernel_launch(void* const* d_in, const int* in_sizes, int n_in,
                              void* d_out, int out_size, void* d_ws, size_t ws_size,
                              hipStream_t stream)
{
  const float* emit   = (const float*)d_in[0];
  const int*   y      = (const int*)d_in[1];
  const float* trans  = (const float*)d_in[2];
  const float* strans = (const float*)d_in[3];
  const float* etrans = (const float*)d_in[4];
  float*  out = (float*)d_out;
  double* ws  = (double*)d_ws;
  uint4*  q4  = (uint4*)((char*)d_ws + 64);   // 16 KB fp8 A-fragments

  hipMemsetAsync(ws, 0, 4 * sizeof(double), stream);
  crf_setup<<<dim3(1), dim3(64), 0, stream>>>(trans, q4);
  crf_main<<<dim3(NFWDB), dim3(256), 0, stream>>>(
      emit, y, trans, strans, etrans, q4, ws, out);
}